// Round 3
// baseline (19818.605 us; speedup 1.0000x reference)
//
#include <hip/hip_runtime.h>
#include <hip/hip_fp16.h>

// LSTM B=8192 S=1024 H=256 — round 3: W-stationary + 2 blocks/CU + split-K overlap.
// 512 blocks x 512 thr; pairs {B, B^8} (same XCD under both dispatch maps) share
// 32 batch rows; each block owns j-half (512 gate rows, interleaved n'=j*4+g,
// 128 KB fp16 = 128 VGPR/thread A-fragments, loaded once).
// Per step: own h-half stays in LDS (ostage, never leaves the CU); only the
// peer half (8 KB) is exchanged via L2 double buffer + flag. DMA issued right
// after the spin; own-half K-loop + acc-init overlap the DMA flight.
// XOR chunk swizzle on the h image: conflict-free b128 reads, coalesced publish.

typedef _Float16 f16x8 __attribute__((ext_vector_type(8)));
typedef float f32x4 __attribute__((ext_vector_type(4)));
typedef unsigned int u32;
typedef unsigned short u16;

#define WINT_OFF 0u
#define W0B_OFF  524288u
#define FLAG_OFF 528384u             // int[512*16] = 32 KB
#define PUB_OFF  1048576u            // u16[2 parity][256 pair][2 mi][4096]
#define PUB_PAR  (256u * 2u * 4096u) // u16 elems per parity (4 MB)

static __device__ __forceinline__ float fast_exp2(float x) {
#if __has_builtin(__builtin_amdgcn_exp2f)
  return __builtin_amdgcn_exp2f(x);
#else
  return exp2f(x);
#endif
}
static __device__ __forceinline__ float fast_rcp(float x) {
#if __has_builtin(__builtin_amdgcn_rcpf)
  return __builtin_amdgcn_rcpf(x);
#else
  return 1.0f / x;
#endif
}
static __device__ __forceinline__ float fsig(float x) {
  return fast_rcp(1.0f + fast_exp2(-1.44269504f * x));
}
static __device__ __forceinline__ float ftanh_(float x) {
  float e = fast_exp2(2.88539008f * x);
  return 1.0f - 2.0f * fast_rcp(e + 1.0f);
}
static __device__ __forceinline__ u16 f16b(float f) {
  union { _Float16 h; u16 u; } cv; cv.h = (_Float16)f; return cv.u;
}
static __device__ __forceinline__ float h2f(u16 u) {
  union { u16 u; _Float16 h; } cv; cv.u = u; return (float)cv.h;
}

// Wint[n'][k], n' = j*4+g (gates of one j adjacent); w0b = packed fp16 {w0, bias}.
__global__ void lstm_prep(const float* __restrict__ Wf, const float* __restrict__ Wi,
                          const float* __restrict__ Wc, const float* __restrict__ Wo,
                          const float* __restrict__ bf_, const float* __restrict__ bi_,
                          const float* __restrict__ bc_, const float* __restrict__ bo_,
                          u16* __restrict__ Wint, u32* __restrict__ w0b) {
  int np = blockIdx.x;      // 0..1023
  int k  = threadIdx.x;     // 0..255
  int g = np & 3, j = np >> 2;
  const float* Ws = (g == 0) ? Wf : (g == 1) ? Wi : (g == 2) ? Wc : Wo;
  Wint[np * 256 + k] = f16b(Ws[j * 257 + 1 + k]);
  if (k == 0) {
    const float* bs = (g == 0) ? bf_ : (g == 1) ? bi_ : (g == 2) ? bc_ : bo_;
    w0b[np] = (u32)f16b(Ws[j * 257]) | ((u32)f16b(bs[j]) << 16);
  }
}

// Zero parity-0 publish buffer (h_0 = 0), flags, and out = bout (blocks atomicAdd partials).
__global__ void lstm_zero(uint4* __restrict__ pub0, uint4* __restrict__ flags,
                          float* __restrict__ out, const float* __restrict__ bout) {
  int idx = blockIdx.x * 256 + threadIdx.x;
  uint4 z = uint4{0, 0, 0, 0};
  if (idx < 262144) pub0[idx] = z;
  else if (idx < 262144 + 2048) flags[idx - 262144] = z;
  else { int o = idx - 264192; if (o < 8192) out[o] = bout[0]; }
}

__global__ __launch_bounds__(512, 4) void lstm_main(
    const u16* __restrict__ Wint, const u32* __restrict__ w0b,
    const float* __restrict__ x, const float* __restrict__ Wout,
    float* __restrict__ out, u16* __restrict__ pub, int* __restrict__ flags) {

  __shared__ __align__(16) u16 ostage[32 * 128];  // own h-half image (swizzled)
  __shared__ __align__(16) u16 pstage[32 * 128];  // peer h-half image
  __shared__ u32 lw0b[512];

  const int tid  = threadIdx.x;
  const int wv   = tid >> 6;       // 0..7
  const int lane = tid & 63;
  const int l15  = lane & 15;
  const int quad = lane >> 4;
  const int B    = blockIdx.x;
  const int mi   = (B >> 3) & 1;
  const int peer = B ^ 8;
  const int pid  = (B & 7) | ((B >> 4) << 3);    // pair 0..255
  const int rows = pid * 32;

  // ---- one-time: W A-fragments into registers (128 VGPRs) ----
  f16x8 wfrag[4][8];
#pragma unroll
  for (int mm = 0; mm < 4; ++mm)
#pragma unroll
    for (int kt = 0; kt < 8; ++kt)
      wfrag[mm][kt] = *(const f16x8*)(Wint +
          (size_t)(mi * 512 + (wv * 4 + mm) * 16 + l15) * 256 + kt * 32 + quad * 8);
  lw0b[tid] = w0b[mi * 512 + tid];
  ((uint4*)ostage)[tid] = uint4{0, 0, 0, 0};     // h_0 own half = 0

  float cst[4][2];
#pragma unroll
  for (int mm = 0; mm < 4; ++mm)
#pragma unroll
    for (int bt = 0; bt < 2; ++bt) cst[mm][bt] = 0.0f;

  const float* xp = x + (size_t)(rows + l15) * 1024;
  u16* mypub       = pub + (size_t)pid * 8192 + mi * 4096;
  const u16* ppub  = pub + (size_t)pid * 8192 + (1 - mi) * 4096;
  int* const myflag = flags + B * 16;
  int* const pflag  = flags + peer * 16;

  __syncthreads();

#pragma unroll 1
  for (int t = 0; t < 1024; ++t) {
    const int pr = t & 1;          // parity holding h_t
    // 1. wait for peer's h_t (each wave independently; usually already set)
    while (__hip_atomic_load(pflag, __ATOMIC_RELAXED, __HIP_MEMORY_SCOPE_AGENT) < t)
      __builtin_amdgcn_s_sleep(1);

    // 2. DMA peer half -> pstage (in flight across steps 3-4)
    __builtin_amdgcn_global_load_lds(
        (const __attribute__((address_space(1))) u32*)(ppub + (size_t)pr * PUB_PAR + tid * 8),
        (__attribute__((address_space(3))) u32*)(pstage + wv * 512), 16, 0, 0);

    // 3. acc init = x*w0 + bias
    float xv[2];
#pragma unroll
    for (int bt = 0; bt < 2; ++bt) xv[bt] = xp[bt * 16 * 1024 + t];
    f32x4 acc[4][2];
#pragma unroll
    for (int mm = 0; mm < 4; ++mm) {
      uint4 pk = *(const uint4*)&lw0b[(wv * 4 + mm) * 16 + quad * 4];
      u32 pka[4] = {pk.x, pk.y, pk.z, pk.w};
#pragma unroll
      for (int bt = 0; bt < 2; ++bt)
#pragma unroll
        for (int r = 0; r < 4; ++r)
          acc[mm][bt][r] = xv[bt] * h2f((u16)pka[r]) + h2f((u16)(pka[r] >> 16));
    }

    // 4. own-half K (reads ostage; overlaps the DMA)
#pragma unroll
    for (int ktl = 0; ktl < 4; ++ktl) {
      f16x8 bo[2];
#pragma unroll
      for (int bt = 0; bt < 2; ++bt) {
        int b = bt * 16 + l15;
        int c = (ktl * 4 + quad) ^ (b & 7);
        bo[bt] = *(const f16x8*)&ostage[b * 128 + c * 8];
      }
#pragma unroll
      for (int mm = 0; mm < 4; ++mm)
#pragma unroll
        for (int bt = 0; bt < 2; ++bt)
          acc[mm][bt] = __builtin_amdgcn_mfma_f32_16x16x32_f16(
              wfrag[mm][mi * 4 + ktl], bo[bt], acc[mm][bt], 0, 0, 0);
    }
    __syncthreads();   // DMA drained; all waves done with ostage h_t

    // 5. peer-half K (reads pstage)
#pragma unroll
    for (int ktl = 0; ktl < 4; ++ktl) {
      f16x8 bp[2];
#pragma unroll
      for (int bt = 0; bt < 2; ++bt) {
        int b = bt * 16 + l15;
        int c = (ktl * 4 + quad) ^ (b & 7);
        bp[bt] = *(const f16x8*)&pstage[b * 128 + c * 8];
      }
#pragma unroll
      for (int mm = 0; mm < 4; ++mm)
#pragma unroll
        for (int bt = 0; bt < 2; ++bt)
          acc[mm][bt] = __builtin_amdgcn_mfma_f32_16x16x32_f16(
              wfrag[mm][(1 - mi) * 4 + ktl], bp[bt], acc[mm][bt], 0, 0, 0);
    }

    // 6. elementwise: f,i,cs,o of one (b,j) in one f32x4; h_{t+1} -> ostage
#pragma unroll
    for (int mm = 0; mm < 4; ++mm) {
      int jl = (wv * 4 + mm) * 4 + quad;   // local j 0..127
#pragma unroll
      for (int bt = 0; bt < 2; ++bt) {
        int b = bt * 16 + l15;
        float fg = acc[mm][bt][0], ig = acc[mm][bt][1];
        float cg = acc[mm][bt][2], og = acc[mm][bt][3];
        float c_ = fsig(fg) * cst[mm][bt] + fsig(ig) * ftanh_(cg);
        cst[mm][bt] = c_;
        float hv = fsig(og) * ftanh_(c_);
        ostage[b * 128 + ((jl >> 3) ^ (b & 7)) * 8 + (jl & 7)] = f16b(hv);
      }
    }
    __syncthreads();   // ostage h_{t+1} complete; all pstage reads done

    // 7. publish own half image (one coalesced uint4/thread)
    uint4 v = ((const uint4*)ostage)[tid];
    *(uint4*)(mypub + (size_t)(pr ^ 1) * PUB_PAR + tid * 8) = v;
    __syncthreads();   // every thread's store drained (vmcnt 0) before flag
    if (tid == 0)
      __hip_atomic_store(myflag, t + 1, __ATOMIC_RELAXED, __HIP_MEMORY_SCOPE_AGENT);
  }

  // ---- out[b] += (own-half h_1024) . Wout  (out pre-set to bout by lstm_zero) ----
  {
    int row = tid >> 4, seg = tid & 15;
    f16x8 hv = *(const f16x8*)&ostage[row * 128 + (seg ^ (row & 7)) * 8];
    float a = 0.0f;
#pragma unroll
    for (int e = 0; e < 8; ++e) a += (float)hv[e] * Wout[mi * 128 + seg * 8 + e];
#pragma unroll
    for (int mask = 1; mask < 16; mask <<= 1) a += __shfl_xor(a, mask, 16);
    if (seg == 0) atomicAdd(&out[rows + row], a);
  }
}

extern "C" void kernel_launch(void* const* d_in, const int* in_sizes, int n_in,
                              void* d_out, int out_size, void* d_ws, size_t ws_size,
                              hipStream_t stream) {
  const float* x    = (const float*)d_in[0];
  const float* Wf   = (const float*)d_in[1];
  const float* bf_  = (const float*)d_in[2];
  const float* Wi   = (const float*)d_in[3];
  const float* bi_  = (const float*)d_in[4];
  const float* Wc   = (const float*)d_in[5];
  const float* bc_  = (const float*)d_in[6];
  const float* Wo   = (const float*)d_in[7];
  const float* bo_  = (const float*)d_in[8];
  const float* Wout = (const float*)d_in[9];
  const float* bout = (const float*)d_in[10];

  u16* Wint  = (u16*)((char*)d_ws + WINT_OFF);
  u32* w0b   = (u32*)((char*)d_ws + W0B_OFF);
  int* flags = (int*)((char*)d_ws + FLAG_OFF);
  u16* pub   = (u16*)((char*)d_ws + PUB_OFF);

  lstm_prep<<<1024, 256, 0, stream>>>(Wf, Wi, Wc, Wo, bf_, bi_, bc_, bo_, Wint, w0b);
  lstm_zero<<<1064, 256, 0, stream>>>((uint4*)pub, (uint4*)flags, (float*)d_out, bout);
  lstm_main<<<512, 512, 0, stream>>>(Wint, w0b, x, Wout, (float*)d_out, pub, flags);
}